// Round 9
// baseline (55.778 us; speedup 1.0000x reference)
//
#include <hip/hip_runtime.h>
#include <math.h>
#include <float.h>

// Problem constants (match reference setup_inputs)
#define BB 8
#define NN 2048
#define BN (BB * NN)
#define BLK 256
#define NSLICE 8                // candidate slices per block (one per 32-thread group)
#define SLICE (NN / NSLICE)     // 256 candidates per thread
#define QPB 32                  // queries per block
#define QSPLIT (NN / QPB)       // 64 query slices per (task,b)
#define NBLOCKS (2 * BB * QSPLIT)  // 1024

// Workspace layout. cham/l1p/cnt are written via RELEASE atomic stores and read
// via ACQUIRE atomic loads (the r3-r6 proven cross-block pattern). gcnt is
// MONOTONIC: only (ticket+1) mod NBLOCKS is tested, so no init needed and the
// 0xAA poison is harmless.
//   float cham[1024]  @ 0
//   float l1p[512]    @ 4096
//   float cnt[512]    @ 6144
//   uint  gcnt        @ 8192
__global__ __launch_bounds__(BLK) void k_one(const float* __restrict__ pred,
                                             const float* __restrict__ target,
                                             const float* __restrict__ points,
                                             const int* __restrict__ mask,
                                             float* __restrict__ cham,
                                             float* __restrict__ l1p,
                                             float* __restrict__ cnt,
                                             unsigned int* __restrict__ gcnt,
                                             float* __restrict__ out) {
    // bid = (task<<9) | (b<<6) | qs   -> 1024 blocks
    int bid = blockIdx.x;
    int qs = bid & (QSPLIT - 1);
    int b = (bid >> 6) & 7;
    int task = bid >> 9;   // 0: query=clean(points+target), cand=predp(points+pred)
                           // 1: query=predp,               cand=clean
    int t = threadIdx.x;
    int q = t & (QPB - 1);      // query lane within block
    int s = t >> 5;             // candidate slice 0..7

    const float* dq = task ? pred : target;   // query delta
    const float* dc = task ? target : pred;   // candidate delta

    // ---- stage ALL 2048 candidates of (task,b) into LDS (32 KB) ----
    __shared__ float4 cand[NN];
    #pragma unroll
    for (int c = 0; c < NN / BLK; ++c) {
        int j = c * BLK + t;
        int g = b * NN + j;
        size_t g3 = (size_t)g * 3;
        float x = 1e30f, y = 1e30f, z = 1e30f;  // invalid: loses every min, stays finite
        if (mask[g]) {
            x = points[g3 + 0] + dc[g3 + 0];
            y = points[g3 + 1] + dc[g3 + 1];
            z = points[g3 + 2] + dc[g3 + 2];
        }
        cand[j] = make_float4(x, y, z, 0.f);
    }

    // ---- query coords (8 threads share a query; L1 serves the redundancy) ----
    int qi = qs * QPB + q;
    size_t gq3 = (size_t)(b * NN + qi) * 3;
    float qx = points[gq3 + 0] + dq[gq3 + 0];
    float qy = points[gq3 + 1] + dq[gq3 + 1];
    float qz = points[gq3 + 2] + dq[gq3 + 2];
    __syncthreads();

    // ---- scan my 256-candidate slice (wave reads = 2-address broadcast, free) ----
    float mn = FLT_MAX;
    const float4* cs = cand + s * SLICE;
    #pragma unroll 8
    for (int j = 0; j < SLICE; j += 2) {
        float4 c0 = cs[j];
        float4 c1 = cs[j + 1];
        float d0 = fabsf(qx - c0.x) + fabsf(qy - c0.y) + fabsf(qz - c0.z);
        float d1 = fabsf(qx - c1.x) + fabsf(qy - c1.y) + fabsf(qz - c1.z);
        mn = fminf(fminf(d0, d1), mn);   // v_min3_f32; min is order-exact
    }

    // ---- fold 8 slice-partials per query inside the block ----
    __shared__ float pm[NSLICE][QPB + 1];
    pm[s][q] = mn;
    __syncthreads();

    float v = 0.f, sl1 = 0.f, scnt = 0.f;
    if (t < QPB) {
        float m0 = pm[0][t];
        #pragma unroll
        for (int ss = 1; ss < NSLICE; ++ss) m0 = fminf(m0, pm[ss][t]);
        int gq = b * NN + qs * QPB + t;
        float mf = (float)mask[gq];
        v = (mf != 0.f) ? m0 : 0.f;
        if (task == 0) {   // fused masked-L1 + valid count (each point covered once)
            size_t g3 = (size_t)gq * 3;
            sl1 = (fabsf(pred[g3 + 0] - target[g3 + 0]) +
                   fabsf(pred[g3 + 1] - target[g3 + 1]) +
                   fabsf(pred[g3 + 2] - target[g3 + 2])) * (1.0f / 3.0f) * mf;
            scnt = mf;
        }
    }
    if (t < 64) {   // all data sits in wave 0 (lanes 32-63 hold zeros)
        for (int off = 32; off; off >>= 1) {
            v    += __shfl_down(v, off, 64);
            sl1  += __shfl_down(sl1, off, 64);
            scnt += __shfl_down(scnt, off, 64);
        }
    }

    // ---- publish block partials (proven release-store pattern), take ticket ----
    __shared__ int isLast;
    if (t == 0) {
        __hip_atomic_store(&cham[bid], v, __ATOMIC_RELEASE, __HIP_MEMORY_SCOPE_AGENT);
        if (task == 0) {
            __hip_atomic_store(&l1p[(b << 6) | qs], sl1, __ATOMIC_RELEASE, __HIP_MEMORY_SCOPE_AGENT);
            __hip_atomic_store(&cnt[(b << 6) | qs], scnt, __ATOMIC_RELEASE, __HIP_MEMORY_SCOPE_AGENT);
        }
        unsigned int tk = __hip_atomic_fetch_add(gcnt, 1u, __ATOMIC_ACQ_REL,
                                                 __HIP_MEMORY_SCOPE_AGENT);
        isLast = (((tk + 1u) & (NBLOCKS - 1)) == 0u);
    }
    __syncthreads();
    if (!isLast) return;

    // ---- finalize in the globally-last block (acquire loads, fixed-order folds) ----
    __shared__ float gsum[16];   // per-(task,b) chamfer sums
    __shared__ float cntb[8];    // per-b valid counts
    __shared__ float l1w[4];     // per-wave l1 partials
    int w = t >> 6, lane = t & 63;

    #pragma unroll
    for (int r = 0; r < 4; ++r) {            // cham: 16 groups of 64 consecutive
        int g = w + r * 4;
        float x = __hip_atomic_load(&cham[(g << 6) | lane], __ATOMIC_ACQUIRE,
                                    __HIP_MEMORY_SCOPE_AGENT);
        for (int off = 32; off; off >>= 1) x += __shfl_down(x, off, 64);
        if (lane == 0) gsum[g] = x;
    }
    #pragma unroll
    for (int r = 0; r < 2; ++r) {            // cnt: 8 groups of 64 consecutive
        int g = w + r * 4;
        float x = __hip_atomic_load(&cnt[(g << 6) | lane], __ATOMIC_ACQUIRE,
                                    __HIP_MEMORY_SCOPE_AGENT);
        for (int off = 32; off; off >>= 1) x += __shfl_down(x, off, 64);
        if (lane == 0) cntb[g] = x;
    }
    {                                         // l1: wave w sums its 128 entries
        float x = __hip_atomic_load(&l1p[w * 128 + lane], __ATOMIC_ACQUIRE,
                                    __HIP_MEMORY_SCOPE_AGENT)
                + __hip_atomic_load(&l1p[w * 128 + 64 + lane], __ATOMIC_ACQUIRE,
                                    __HIP_MEMORY_SCOPE_AGENT);
        for (int off = 32; off; off >>= 1) x += __shfl_down(x, off, 64);
        if (lane == 0) l1w[w] = x;
    }
    __syncthreads();
    if (t == 0) {
        double l1num = (double)l1w[0] + (double)l1w[1] + (double)l1w[2] + (double)l1w[3];
        double msum = 0.0;
        for (int b2 = 0; b2 < BB; ++b2) msum += (double)cntb[b2];
        double l1 = l1num / msum;
        double cd = 0.0;
        for (int b2 = 0; b2 < BB; ++b2)
            cd += ((double)gsum[b2] + (double)gsum[8 + b2]) / (double)cntb[b2];
        cd *= (1.0 / BB);
        out[0] = (float)(l1 + exp(-l1) * cd);
    }
}

extern "C" void kernel_launch(void* const* d_in, const int* in_sizes, int n_in,
                              void* d_out, int out_size, void* d_ws, size_t ws_size,
                              hipStream_t stream) {
    const float* pred   = (const float*)d_in[0];
    const float* target = (const float*)d_in[1];
    const int*   mask   = (const int*)d_in[2];
    const float* points = (const float*)d_in[3];
    float* out = (float*)d_out;

    float* cham = (float*)d_ws;
    float* l1p  = (float*)((char*)d_ws + 4096);
    float* cnt  = (float*)((char*)d_ws + 6144);
    unsigned int* gcnt = (unsigned int*)((char*)d_ws + 8192);

    k_one<<<NBLOCKS, BLK, 0, stream>>>(pred, target, points, mask,
                                       cham, l1p, cnt, gcnt, out);
}

// Round 10
// 23.347 us; speedup vs baseline: 2.3891x; 2.3891x over previous
//
#include <hip/hip_runtime.h>
#include <math.h>
#include <float.h>

// Problem constants (match reference setup_inputs)
#define BB 8
#define NN 2048
#define BN (BB * NN)
#define BLK 256
#define Q 4                     // queries per thread (consecutive -> float4 I/O)
#define QSPLIT 2                // query slices per (task,b): 2 * 1024 = 2048
#define QSLICE (BLK * Q)        // 1024 queries per block
#define CSPLIT 64               // candidate splits per (task,batch)
#define CCHUNK (NN / CSPLIT)    // 32 candidates staged per block
#define NBLOCKS (2 * BB * QSPLIT * CSPLIT)   // 2048: 8 blocks/CU, 8 waves/SIMD
#define RBLOCKS 32              // fold blocks: 32*256 threads*4 q = 2*BN

// Workspace layout (every data slot written every call; gcnt is MONOTONIC --
// only (ticket+1) mod RBLOCKS tested -- so no init needed, 0xAA poison harmless):
//   float minpart[CSPLIT][2*BN]   @ 0          (8 MB)
//   float champart[32]            @ 8 MB       (release-stored, acquire-loaded)
//   float l1part[16]              @ +128
//   float cntpart[16]             @ +192
//   uint  gcnt                    @ +256
#define MINPART_FLOATS (CSPLIT * 2 * BN)

__global__ __launch_bounds__(BLK) void k_main(const float* __restrict__ pred,
                                              const float* __restrict__ target,
                                              const float* __restrict__ points,
                                              const int* __restrict__ mask,
                                              float* __restrict__ minpart,
                                              float* __restrict__ l1part,
                                              float* __restrict__ cntpart) {
    // bid bits: cs(6) | qs(1) | b(3) | task(1)  -> 2048 blocks
    int bid = blockIdx.x;
    int cs = bid & (CSPLIT - 1);
    int qs = (bid >> 6) & (QSPLIT - 1);
    int b = (bid >> 7) & 7;
    int task = bid >> 10;  // 0: query=clean(points+target), cand=predp(points+pred)
                           // 1: query=predp,               cand=clean
    int t = threadIdx.x;

    const float* dq = task ? pred : target;   // query delta
    const float* dc = task ? target : pred;   // candidate delta

    __shared__ float4 cand[CCHUNK];
    if (t < CCHUNK) {
        int g = b * NN + cs * CCHUNK + t;
        size_t g3 = (size_t)g * 3;
        float x = 1e30f, y = 1e30f, z = 1e30f;  // invalid: loses every min, stays finite
        if (mask[g]) {
            x = points[g3 + 0] + dc[g3 + 0];
            y = points[g3 + 1] + dc[g3 + 1];
            z = points[g3 + 2] + dc[g3 + 2];
        }
        cand[t] = make_float4(x, y, z, 0.f);
    }
    __syncthreads();

    // thread t owns 4 consecutive queries qi0..qi0+3 -> float4-friendly I/O
    int qi0 = qs * QSLICE + 4 * t;
    float qx[Q], qy[Q], qz[Q], mn[Q];
    {
        size_t g3 = (size_t)(b * NN + qi0) * 3;   // multiple of 12 -> 16B aligned
        const float4* p4 = (const float4*)(points + g3);
        const float4* d4 = (const float4*)(dq + g3);
        float4 a0 = p4[0], a1 = p4[1], a2 = p4[2];
        float4 e0 = d4[0], e1 = d4[1], e2 = d4[2];
        qx[0] = a0.x + e0.x; qy[0] = a0.y + e0.y; qz[0] = a0.z + e0.z;
        qx[1] = a0.w + e0.w; qy[1] = a1.x + e1.x; qz[1] = a1.y + e1.y;
        qx[2] = a1.z + e1.z; qy[2] = a1.w + e1.w; qz[2] = a2.x + e2.x;
        qx[3] = a2.y + e2.y; qy[3] = a2.z + e2.z; qz[3] = a2.w + e2.w;
        #pragma unroll
        for (int q = 0; q < Q; ++q) mn[q] = FLT_MAX;
    }

    #pragma unroll 8
    for (int j = 0; j < CCHUNK; j += 2) {
        float4 c0 = cand[j];       // wave-uniform broadcast, conflict-free
        float4 c1 = cand[j + 1];
        #pragma unroll
        for (int q = 0; q < Q; ++q) {
            float d0 = fabsf(qx[q] - c0.x) + fabsf(qy[q] - c0.y) + fabsf(qz[q] - c0.z);
            float d1 = fabsf(qx[q] - c1.x) + fabsf(qy[q] - c1.y) + fabsf(qz[q] - c1.z);
            mn[q] = fminf(fminf(d0, d1), mn[q]);   // v_min3_f32; min is order-exact
        }
    }

    // non-atomic partial-min store: one float4 slot per (cs, task, b, qi0)
    {
        float* mp = minpart + (size_t)cs * (2 * BN) + (size_t)task * BN + b * NN + qi0;
        *(float4*)mp = make_float4(mn[0], mn[1], mn[2], mn[3]);
    }

    // Fused masked-L1 + valid-count: 16 blocks (task0, cs0), 4 consecutive pts/thread
    if (task == 0 && cs == 0) {
        size_t g3 = (size_t)(b * NN + qi0) * 3;
        const float4* p4 = (const float4*)(pred + g3);
        const float4* t4 = (const float4*)(target + g3);
        const int4 m4 = *(const int4*)(mask + b * NN + qi0);
        float4 u0 = p4[0], u1 = p4[1], u2 = p4[2];
        float4 v0 = t4[0], v1 = t4[1], v2 = t4[2];
        float mf[Q] = { (float)m4.x, (float)m4.y, (float)m4.z, (float)m4.w };
        float l[Q];
        l[0] = fabsf(u0.x - v0.x) + fabsf(u0.y - v0.y) + fabsf(u0.z - v0.z);
        l[1] = fabsf(u0.w - v0.w) + fabsf(u1.x - v1.x) + fabsf(u1.y - v1.y);
        l[2] = fabsf(u1.z - v1.z) + fabsf(u1.w - v1.w) + fabsf(u2.x - v2.x);
        l[3] = fabsf(u2.y - v2.y) + fabsf(u2.z - v2.z) + fabsf(u2.w - v2.w);
        float s = 0.f, c = 0.f;
        #pragma unroll
        for (int q = 0; q < Q; ++q) { s += l[q] * (1.0f / 3.0f) * mf[q]; c += mf[q]; }
        for (int off = 32; off; off >>= 1) {
            s += __shfl_down(s, off, 64);
            c += __shfl_down(c, off, 64);
        }
        __shared__ float ls[4], lc[4];
        if ((t & 63) == 0) { ls[t >> 6] = s; lc[t >> 6] = c; }
        __syncthreads();   // block-uniform branch (task, cs are block constants)
        if (t == 0) {
            l1part[b * QSPLIT + qs]  = ls[0] + ls[1] + ls[2] + ls[3];
            cntpart[b * QSPLIT + qs] = lc[0] + lc[1] + lc[2] + lc[3];
        }
    }
}

__global__ __launch_bounds__(BLK) void k_redfin(const float* __restrict__ minpart,
                                                const int* __restrict__ mask,
                                                const float* __restrict__ l1part,
                                                const float* __restrict__ cntpart,
                                                float* __restrict__ champart,
                                                unsigned int* __restrict__ gcnt,
                                                float* __restrict__ out) {
    // 32 blocks; block covers 1024 consecutive queries (one (task,b) half-slice)
    // bid = (task<<4) | (b<<1) | half
    int bid = blockIdx.x;
    int t = threadIdx.x;
    int q0 = bid * 1024 + 4 * t;          // global query index (over 2*BN), float4 slot

    float4 m0 = *(const float4*)(minpart + q0);
    #pragma unroll
    for (int p = 1; p < CSPLIT; ++p) {
        float4 mp = *(const float4*)(minpart + (size_t)p * (2 * BN) + q0);
        m0.x = fminf(m0.x, mp.x); m0.y = fminf(m0.y, mp.y);
        m0.z = fminf(m0.z, mp.z); m0.w = fminf(m0.w, mp.w);
    }
    const int4 m4 = *(const int4*)(mask + (q0 & (BN - 1)));
    float v = (m4.x ? m0.x : 0.f) + (m4.y ? m0.y : 0.f)
            + (m4.z ? m0.z : 0.f) + (m4.w ? m0.w : 0.f);

    for (int off = 32; off; off >>= 1) v += __shfl_down(v, off, 64);

    __shared__ float fls[4];
    __shared__ int isLast;
    __shared__ float ch[RBLOCKS];
    if ((t & 63) == 0) fls[t >> 6] = v;
    __syncthreads();
    if (t == 0) {
        float bs = fls[0] + fls[1] + fls[2] + fls[3];
        __hip_atomic_store(&champart[bid], bs, __ATOMIC_RELEASE, __HIP_MEMORY_SCOPE_AGENT);
        unsigned int tk = __hip_atomic_fetch_add(gcnt, 1u, __ATOMIC_ACQ_REL,
                                                 __HIP_MEMORY_SCOPE_AGENT);
        isLast = (((tk + 1u) & (RBLOCKS - 1)) == 0u);
    }
    __syncthreads();
    if (!isLast) return;

    // globally-last block finalizes (acquire loads pair with release stores)
    if (t < RBLOCKS)
        ch[t] = __hip_atomic_load(&champart[t], __ATOMIC_ACQUIRE, __HIP_MEMORY_SCOPE_AGENT);
    __syncthreads();
    if (t == 0) {
        double cnt[BB], msum = 0.0, l1num = 0.0;
        for (int b2 = 0; b2 < BB; ++b2) {
            double cb = 0.0;
            for (int k = 0; k < QSPLIT; ++k) {
                cb += (double)cntpart[b2 * QSPLIT + k];
                l1num += (double)l1part[b2 * QSPLIT + k];
            }
            cnt[b2] = cb;
            msum += cb;
        }
        double l1 = l1num / msum;
        double cd = 0.0;
        for (int b2 = 0; b2 < BB; ++b2) {
            // ch[(task<<4)|(b<<1)|half]
            double chb = (double)ch[(b2 << 1)] + (double)ch[(b2 << 1) | 1]
                       + (double)ch[16 | (b2 << 1)] + (double)ch[16 | (b2 << 1) | 1];
            cd += chb / cnt[b2];
        }
        cd *= (1.0 / BB);
        out[0] = (float)(l1 + exp(-l1) * cd);
    }
}

extern "C" void kernel_launch(void* const* d_in, const int* in_sizes, int n_in,
                              void* d_out, int out_size, void* d_ws, size_t ws_size,
                              hipStream_t stream) {
    const float* pred   = (const float*)d_in[0];
    const float* target = (const float*)d_in[1];
    const int*   mask   = (const int*)d_in[2];
    const float* points = (const float*)d_in[3];
    float* out = (float*)d_out;

    float* minpart  = (float*)d_ws;
    char* tail = (char*)d_ws + (size_t)MINPART_FLOATS * 4;
    float* champart = (float*)tail;
    float* l1part   = (float*)(tail + 128);
    float* cntpart  = (float*)(tail + 192);
    unsigned int* gcnt = (unsigned int*)(tail + 256);

    k_main<<<NBLOCKS, BLK, 0, stream>>>(pred, target, points, mask,
                                        minpart, l1part, cntpart);
    k_redfin<<<RBLOCKS, BLK, 0, stream>>>(minpart, mask, l1part, cntpart,
                                          champart, gcnt, out);
}